// Round 5
// baseline (11648.636 us; speedup 1.0000x reference)
//
#include <hip/hip_runtime.h>

#define NCA_ALPHA 0.1f

// ---------- helpers ----------
__device__ __forceinline__ float4 ld4(const float* p) { return *(const float4*)p; }
__device__ __forceinline__ void st4(float* p, float4 v) { *(float4*)p = v; }
__device__ __forceinline__ float4 add4(float4 a, float4 b) {
  return make_float4(a.x + b.x, a.y + b.y, a.z + b.z, a.w + b.w);
}
__device__ __forceinline__ float4 zero4() { return make_float4(0.f, 0.f, 0.f, 0.f); }

// Level-0 float index with XOR swizzle tuned for the 1024-thread lane layout
// (lanes: b = tid[5:2], dq = tid[1:0], d = 4*dq+i). Granule column =
// ((4dq+i)^(b&3) , dq&1) spans all 8 columns -> conflict-free ds_*_b128.
// Bijection: flips d's low 2 bits keyed by b&3; applied to EVERY S0 access.
__device__ __forceinline__ int ix0(int a, int b, int d) {
  return (((a * 16 + b) * 16 + d) * 4) ^ ((b & 3) << 2);
}
__device__ __forceinline__ int ix1(int a, int b, int d) { return ((a * 8 + b) * 8 + d) * 4; }
__device__ __forceinline__ int ix2(int a, int b, int d) { return ((a * 4 + b) * 4 + d) * 4; }

__device__ __forceinline__ void fma_row32(float hid[32], float v, const float* __restrict__ w) {
#pragma unroll
  for (int j = 0; j < 32; ++j) hid[j] = fmaf(v, w[j], hid[j]);
}
__device__ __forceinline__ void fma_row16(float hid[16], float v, const float* __restrict__ w) {
#pragma unroll
  for (int j = 0; j < 16; ++j) hid[j] = fmaf(v, w[j], hid[j]);
}

// relu + full-width (32x4) second layer + residual + clip
__device__ __forceinline__ float4 mlp_tail32(const float hid[32], const float* __restrict__ W2,
                                             const float* __restrict__ B2, float4 c4) {
  float d0 = B2[0], d1 = B2[1], d2 = B2[2], d3 = B2[3];
#pragma unroll
  for (int j = 0; j < 32; ++j) {
    float h = fmaxf(hid[j], 0.0f);
    d0 = fmaf(h, W2[4 * j + 0], d0);
    d1 = fmaf(h, W2[4 * j + 1], d1);
    d2 = fmaf(h, W2[4 * j + 2], d2);
    d3 = fmaf(h, W2[4 * j + 3], d3);
  }
  float4 nv;
  nv.x = fminf(fmaxf(fmaf(NCA_ALPHA, d0, c4.x), -1.0f), 1.0f);
  nv.y = fminf(fmaxf(fmaf(NCA_ALPHA, d1, c4.y), -1.0f), 1.0f);
  nv.z = fminf(fmaxf(fmaf(NCA_ALPHA, d2, c4.z), -1.0f), 1.0f);
  nv.w = fminf(fmaxf(fmaf(NCA_ALPHA, d3, c4.w), -1.0f), 1.0f);
  return nv;
}

// 8 perception rows (identity + laplacian per channel), width-16 variant
__device__ __forceinline__ void p_rows16(float hid[16], float4 c4, float4 nb,
                                         const float* __restrict__ W1h) {
  float lx = fmaf(-6.0f, c4.x, nb.x);
  float ly = fmaf(-6.0f, c4.y, nb.y);
  float lz = fmaf(-6.0f, c4.z, nb.z);
  float lw = fmaf(-6.0f, c4.w, nb.w);
  fma_row16(hid, c4.x, W1h + 0 * 32);
  fma_row16(hid, lx, W1h + 1 * 32);
  fma_row16(hid, c4.y, W1h + 2 * 32);
  fma_row16(hid, ly, W1h + 3 * 32);
  fma_row16(hid, c4.z, W1h + 4 * 32);
  fma_row16(hid, lz, W1h + 5 * 32);
  fma_row16(hid, c4.w, W1h + 6 * 32);
  fma_row16(hid, lw, W1h + 7 * 32);
}
__device__ __forceinline__ void p_rows32(float hid[32], float4 c4, float4 nb,
                                         const float* __restrict__ W1) {
  float lx = fmaf(-6.0f, c4.x, nb.x);
  float ly = fmaf(-6.0f, c4.y, nb.y);
  float lz = fmaf(-6.0f, c4.z, nb.z);
  float lw = fmaf(-6.0f, c4.w, nb.w);
  fma_row32(hid, c4.x, W1 + 0);
  fma_row32(hid, lx, W1 + 32);
  fma_row32(hid, c4.y, W1 + 64);
  fma_row32(hid, ly, W1 + 96);
  fma_row32(hid, c4.z, W1 + 128);
  fma_row32(hid, lz, W1 + 160);
  fma_row32(hid, c4.w, W1 + 192);
  fma_row32(hid, lw, W1 + 224);
}

// LDS float layout (double-buffered, 37376 floats = 149504 B):
//   S0[2]: 0, 16384   S1[2]: 32768, 34816   S2[2]: 36864, 37120
//
// Register budget: __launch_bounds__ arg-2 proved ineffective (r3 (1024,4) and
// r4 (1024,1) both -> VGPR 64 + 21 GB scratch re-read traffic: the backend's
// default occupancy heuristic targets 8 waves/EU at 1024-thread blocks).
// amdgpu_waves_per_eu(4,4) pins the allocator to the real occupancy (one
// LDS-capped block = 16 waves/CU = 4 waves/EU) -> 512/4 = 128 VGPRs, no spill.
extern "C" __global__ void __launch_bounds__(1024)
__attribute__((amdgpu_waves_per_eu(4, 4)))
nca_fused(const float* __restrict__ x, const float* __restrict__ pw1,
          const float* __restrict__ pb1, const float* __restrict__ pw2,
          const float* __restrict__ pb2, const float* __restrict__ cw,
          const float* __restrict__ cb, float* __restrict__ out) {
  extern __shared__ float4 ldsv[];
  float* lds = (float*)ldsv;  // runtime cast: keeps S0/S1/S2 initializers
                              // non-constant (backend can't lower a constant
                              // addrspace(3)->generic cast in an initializer)
  const int tid = threadIdx.x;
  const int bid = blockIdx.x;

  float* S0[2] = {lds, lds + 16384};
  float* S1[2] = {lds + 32768, lds + 34816};
  float* S2[2] = {lds + 36864, lds + 37120};

  // ---- init buffer 0 only (every cell of buffer "next" is fully written each step)
  {
    float4* z0 = (float4*)S0[0];
#pragma unroll
    for (int i = 0; i < 4; ++i) z0[tid + 1024 * i] = zero4();  // 4096 float4
    if (tid < 512) ((float4*)S1[0])[tid] = zero4();            // 512 float4
    if (tid < 64) ((float4*)S2[0])[tid] = zero4();             // 64 float4
  }
  __syncthreads();
  if (tid < 256) {  // set_input: (x>0.5) into ch0 of d=8 slab
    float v = x[bid * 256 + tid];
    int i = tid >> 4, j = tid & 15;
    S0[0][ix0(i, j, 8)] = (v > 0.5f) ? 1.0f : 0.0f;
  }
  __syncthreads();

  // level-0 lane mapping: column of 4 cells in d
  const int la = tid >> 6, lb = (tid >> 2) & 15, dq = tid & 3;
  // level-1 pair mapping
  const int c1 = tid >> 1, half = tid & 1;
  const int a1 = c1 >> 6, b1c = (c1 >> 3) & 7, d1 = c1 & 7;
  // level-2 pair mapping (tid < 128)
  const int c2 = (tid >> 1) & 63;
  const int a2 = c2 >> 4, b2c = (c2 >> 2) & 3, d2 = c2 & 3;

#pragma unroll 1
  for (int t = 0; t < 15; ++t) {
    const int cur = t & 1;
    const float* s0c = S0[cur];
    float* s0n = S0[cur ^ 1];
    const float* s1c = S1[cur];
    float* s1n = S1[cur ^ 1];
    const float* s2c = S2[cur];
    float* s2n = S2[cur ^ 1];

    // ---------------- level 0: 4 cells (d = 4*dq .. 4*dq+3) ----------------
    {
      const float* W1 = pw1;
      const float* W2 = pw2;
#pragma unroll 1
      for (int dp = 0; dp < 2; ++dp) {
        // above-cell is shared by the two fine cells of this d-pair: fold once
        float4 ab = ld4(s1c + ix1(la >> 1, lb >> 1, 2 * dq + dp));
        float ac[32];
#pragma unroll
        for (int j = 0; j < 32; ++j) ac[j] = fmaf(ab.x, W1[384 + j], pb1[j]);
        fma_row32(ac, ab.y, W1 + 416);
        fma_row32(ac, ab.z, W1 + 448);
        fma_row32(ac, ab.w, W1 + 480);
#pragma unroll 1
        for (int i2 = 0; i2 < 2; ++i2) {
          const int d = 4 * dq + 2 * dp + i2;
          float4 c4 = ld4(s0c + ix0(la, lb, d));
          float4 nb = zero4();
          if (la > 0) nb = add4(nb, ld4(s0c + ix0(la - 1, lb, d)));   // wave-uniform
          if (la < 15) nb = add4(nb, ld4(s0c + ix0(la + 1, lb, d)));  // wave-uniform
          if (lb > 0) nb = add4(nb, ld4(s0c + ix0(la, lb - 1, d)));
          if (lb < 15) nb = add4(nb, ld4(s0c + ix0(la, lb + 1, d)));
          if (d > 0) nb = add4(nb, ld4(s0c + ix0(la, lb, d - 1)));
          if (d < 15) nb = add4(nb, ld4(s0c + ix0(la, lb, d + 1)));
          float hid[32];
#pragma unroll
          for (int j = 0; j < 32; ++j) hid[j] = ac[j];
          p_rows32(hid, c4, nb, W1);  // below==0 at level 0
          st4(s0n + ix0(la, lb, d), mlp_tail32(hid, W2, pb2, c4));
        }
      }
    }

    // ---------------- level 1: thread-pair per cell, 16 hidden units each ----------------
    {
      const float* W1h = pw1 + 512 + 16 * half;  // rows stride 32
      const float* B1 = pb1 + 32 + 16 * half;
      const float* W2 = pw2 + 128;
      const float* B2 = pb2 + 4;
      float4 c4 = ld4(s1c + ix1(a1, b1c, d1));
      float4 nb = zero4();
      if (a1 > 0) nb = add4(nb, ld4(s1c + ix1(a1 - 1, b1c, d1)));
      if (a1 < 7) nb = add4(nb, ld4(s1c + ix1(a1 + 1, b1c, d1)));
      if (b1c > 0) nb = add4(nb, ld4(s1c + ix1(a1, b1c - 1, d1)));
      if (b1c < 7) nb = add4(nb, ld4(s1c + ix1(a1, b1c + 1, d1)));
      if (d1 > 0) nb = add4(nb, ld4(s1c + ix1(a1, b1c, d1 - 1)));
      if (d1 < 7) nb = add4(nb, ld4(s1c + ix1(a1, b1c, d1 + 1)));
      float4 bl = zero4();
#pragma unroll
      for (int q = 0; q < 8; ++q)
        bl = add4(bl, ld4(s0c + ix0(2 * a1 + (q >> 2), 2 * b1c + ((q >> 1) & 1),
                                    2 * d1 + (q & 1))));
      bl.x *= 0.125f; bl.y *= 0.125f; bl.z *= 0.125f; bl.w *= 0.125f;
      float4 ab = ld4(s2c + ix2(a1 >> 1, b1c >> 1, d1 >> 1));
      float hid[16];
#pragma unroll
      for (int j = 0; j < 16; ++j) hid[j] = B1[j];
      p_rows16(hid, c4, nb, W1h);
      fma_row16(hid, bl.x, W1h + 8 * 32);
      fma_row16(hid, bl.y, W1h + 9 * 32);
      fma_row16(hid, bl.z, W1h + 10 * 32);
      fma_row16(hid, bl.w, W1h + 11 * 32);
      fma_row16(hid, ab.x, W1h + 12 * 32);
      fma_row16(hid, ab.y, W1h + 13 * 32);
      fma_row16(hid, ab.z, W1h + 14 * 32);
      fma_row16(hid, ab.w, W1h + 15 * 32);
      float e0 = 0.f, e1 = 0.f, e2 = 0.f, e3 = 0.f;
#pragma unroll
      for (int j = 0; j < 16; ++j) {
        float h = fmaxf(hid[j], 0.0f);
        const float* w2r = W2 + (16 * half + j) * 4;
        e0 = fmaf(h, w2r[0], e0);
        e1 = fmaf(h, w2r[1], e1);
        e2 = fmaf(h, w2r[2], e2);
        e3 = fmaf(h, w2r[3], e3);
      }
      e0 += __shfl_xor(e0, 1);
      e1 += __shfl_xor(e1, 1);
      e2 += __shfl_xor(e2, 1);
      e3 += __shfl_xor(e3, 1);
      float4 nv;
      nv.x = fminf(fmaxf(fmaf(NCA_ALPHA, e0 + B2[0], c4.x), -1.0f), 1.0f);
      nv.y = fminf(fmaxf(fmaf(NCA_ALPHA, e1 + B2[1], c4.y), -1.0f), 1.0f);
      nv.z = fminf(fmaxf(fmaf(NCA_ALPHA, e2 + B2[2], c4.z), -1.0f), 1.0f);
      nv.w = fminf(fmaxf(fmaf(NCA_ALPHA, e3 + B2[3], c4.w), -1.0f), 1.0f);
      if (half == 0) st4(s1n + ix1(a1, b1c, d1), nv);
    }

    // ---------------- level 2: thread-pair per cell (tid<128) ----------------
    if (tid < 128) {
      const float* W1h = pw1 + 1024 + 16 * half;
      const float* B1 = pb1 + 64 + 16 * half;
      const float* W2 = pw2 + 256;
      const float* B2 = pb2 + 8;
      float4 c4 = ld4(s2c + ix2(a2, b2c, d2));
      float4 nb = zero4();
      if (a2 > 0) nb = add4(nb, ld4(s2c + ix2(a2 - 1, b2c, d2)));
      if (a2 < 3) nb = add4(nb, ld4(s2c + ix2(a2 + 1, b2c, d2)));
      if (b2c > 0) nb = add4(nb, ld4(s2c + ix2(a2, b2c - 1, d2)));
      if (b2c < 3) nb = add4(nb, ld4(s2c + ix2(a2, b2c + 1, d2)));
      if (d2 > 0) nb = add4(nb, ld4(s2c + ix2(a2, b2c, d2 - 1)));
      if (d2 < 3) nb = add4(nb, ld4(s2c + ix2(a2, b2c, d2 + 1)));
      float4 bl = zero4();
#pragma unroll
      for (int q = 0; q < 8; ++q)
        bl = add4(bl, ld4(s1c + ix1(2 * a2 + (q >> 2), 2 * b2c + ((q >> 1) & 1),
                                    2 * d2 + (q & 1))));
      bl.x *= 0.125f; bl.y *= 0.125f; bl.z *= 0.125f; bl.w *= 0.125f;
      float hid[16];
#pragma unroll
      for (int j = 0; j < 16; ++j) hid[j] = B1[j];
      p_rows16(hid, c4, nb, W1h);
      fma_row16(hid, bl.x, W1h + 8 * 32);
      fma_row16(hid, bl.y, W1h + 9 * 32);
      fma_row16(hid, bl.z, W1h + 10 * 32);
      fma_row16(hid, bl.w, W1h + 11 * 32);
      // above == 0 at top level
      float e0 = 0.f, e1 = 0.f, e2 = 0.f, e3 = 0.f;
#pragma unroll
      for (int j = 0; j < 16; ++j) {
        float h = fmaxf(hid[j], 0.0f);
        const float* w2r = W2 + (16 * half + j) * 4;
        e0 = fmaf(h, w2r[0], e0);
        e1 = fmaf(h, w2r[1], e1);
        e2 = fmaf(h, w2r[2], e2);
        e3 = fmaf(h, w2r[3], e3);
      }
      e0 += __shfl_xor(e0, 1);
      e1 += __shfl_xor(e1, 1);
      e2 += __shfl_xor(e2, 1);
      e3 += __shfl_xor(e3, 1);
      float4 nv;
      nv.x = fminf(fmaxf(fmaf(NCA_ALPHA, e0 + B2[0], c4.x), -1.0f), 1.0f);
      nv.y = fminf(fmaxf(fmaf(NCA_ALPHA, e1 + B2[1], c4.y), -1.0f), 1.0f);
      nv.z = fminf(fmaxf(fmaf(NCA_ALPHA, e2 + B2[2], c4.z), -1.0f), 1.0f);
      nv.w = fminf(fmaxf(fmaf(NCA_ALPHA, e3 + B2[3], c4.w), -1.0f), 1.0f);
      if (half == 0) st4(s2n + ix2(a2, b2c, d2), nv);
    }

    __syncthreads();  // reads from [cur], writes to [cur^1]: one barrier per step
  }

  // ---------------- classifier: feats(256) @ cls_w(256,10) + cls_b ----------------
  if (tid < 256) {
    double v = (double)S2[1][tid];  // 15 steps -> buffer 1; linear == reshape order
    const float* wr = cw + tid * 10;
    double p[10];
#pragma unroll
    for (int o = 0; o < 10; ++o) p[o] = v * (double)wr[o];
#pragma unroll
    for (int off = 32; off > 0; off >>= 1) {
#pragma unroll
      for (int o = 0; o < 10; ++o) p[o] += __shfl_down(p[o], off);
    }
    if ((tid & 63) == 0) {
      double* red = (double*)S0[0];  // dead after the loop; 40 doubles
      int wv = tid >> 6;
#pragma unroll
      for (int o = 0; o < 10; ++o) red[wv * 10 + o] = p[o];
    }
  }
  __syncthreads();
  if (tid < 10) {
    const double* red = (const double*)S0[0];
    double r = (double)cb[tid] + red[tid] + red[10 + tid] + red[20 + tid] + red[30 + tid];
    out[bid * 10 + tid] = (float)r;
  }
}

extern "C" void kernel_launch(void* const* d_in, const int* in_sizes, int n_in,
                              void* d_out, int out_size, void* d_ws, size_t ws_size,
                              hipStream_t stream) {
  const float* x = (const float*)d_in[0];
  const float* w1 = (const float*)d_in[1];
  const float* b1 = (const float*)d_in[2];
  const float* w2 = (const float*)d_in[3];
  const float* b2 = (const float*)d_in[4];
  const float* cw = (const float*)d_in[5];
  const float* cb = (const float*)d_in[6];
  float* out = (float*)d_out;

  const int B = in_sizes[0] / 256;             // 2048
  const size_t shmem = 37376 * sizeof(float);  // 149504 B
  (void)hipFuncSetAttribute((const void*)nca_fused,
                            hipFuncAttributeMaxDynamicSharedMemorySize, (int)shmem);
  nca_fused<<<dim3(B), dim3(1024), shmem, stream>>>(x, w1, b1, w2, b2, cw, cb, out);
}

// Round 6
// 4332.960 us; speedup vs baseline: 2.6884x; 2.6884x over previous
//
#include <hip/hip_runtime.h>

#define NCA_ALPHA 0.1f

// ---------- helpers ----------
__device__ __forceinline__ float4 ld4(const float* p) { return *(const float4*)p; }
__device__ __forceinline__ void st4(float* p, float4 v) { *(float4*)p = v; }
__device__ __forceinline__ float4 add4(float4 a, float4 b) {
  return make_float4(a.x + b.x, a.y + b.y, a.z + b.z, a.w + b.w);
}
__device__ __forceinline__ float4 zero4() { return make_float4(0.f, 0.f, 0.f, 0.f); }

// Level-0 swizzle (r1-proven layout for the 512-thread 2x2x2-group mapping).
__device__ __forceinline__ int ix0(int a, int b, int d) {
  return (((a * 16 + b) * 16 + d) * 4) ^ (((b >> 1) & 1) << 2);
}
__device__ __forceinline__ int ix1(int a, int b, int d) { return ((a * 8 + b) * 8 + d) * 4; }
__device__ __forceinline__ int ix2(int a, int b, int d) { return ((a * 4 + b) * 4 + d) * 4; }

__device__ __forceinline__ void fma_row16(float hid[16], float v, const float* __restrict__ w) {
#pragma unroll
  for (int j = 0; j < 16; ++j) hid[j] = fmaf(v, w[j], hid[j]);
}

// 8 perception rows (identity + laplacian per channel), 16-wide half.
// W1h = W1 + 16*half; rows stride 32.
__device__ __forceinline__ void p_rows16(float hid[16], float4 c4, float4 nb,
                                         const float* __restrict__ W1h) {
  float lx = fmaf(-6.0f, c4.x, nb.x);
  float ly = fmaf(-6.0f, c4.y, nb.y);
  float lz = fmaf(-6.0f, c4.z, nb.z);
  float lw = fmaf(-6.0f, c4.w, nb.w);
  fma_row16(hid, c4.x, W1h + 0 * 32);
  fma_row16(hid, lx, W1h + 1 * 32);
  fma_row16(hid, c4.y, W1h + 2 * 32);
  fma_row16(hid, ly, W1h + 3 * 32);
  fma_row16(hid, c4.z, W1h + 4 * 32);
  fma_row16(hid, lz, W1h + 5 * 32);
  fma_row16(hid, c4.w, W1h + 6 * 32);
  fma_row16(hid, lw, W1h + 7 * 32);
}

// relu + 16-row slice of the (32,4) second layer, accumulating into d[4].
// W2h = W2 + 64*half (rows 16h..16h+15).
__device__ __forceinline__ void tail16(const float hid[16], const float* __restrict__ W2h,
                                       float& d0, float& d1, float& d2, float& d3) {
#pragma unroll
  for (int j = 0; j < 16; ++j) {
    float h = fmaxf(hid[j], 0.0f);
    d0 = fmaf(h, W2h[4 * j + 0], d0);
    d1 = fmaf(h, W2h[4 * j + 1], d1);
    d2 = fmaf(h, W2h[4 * j + 2], d2);
    d3 = fmaf(h, W2h[4 * j + 3], d3);
  }
}

__device__ __forceinline__ float4 clip_res(float4 c4, float d0, float d1, float d2, float d3) {
  float4 nv;
  nv.x = fminf(fmaxf(fmaf(NCA_ALPHA, d0, c4.x), -1.0f), 1.0f);
  nv.y = fminf(fmaxf(fmaf(NCA_ALPHA, d1, c4.y), -1.0f), 1.0f);
  nv.z = fminf(fmaxf(fmaf(NCA_ALPHA, d2, c4.z), -1.0f), 1.0f);
  nv.w = fminf(fmaxf(fmaf(NCA_ALPHA, d3, c4.w), -1.0f), 1.0f);
  return nv;
}

// LDS float layout (double-buffered, 37376 floats = 149504 B):
//   S0[2]: 0, 16384   S1[2]: 32768, 34816   S2[2]: 36864, 37120
//
// 512-thread blocks ONLY: r1 evidence shows the allocator grants ~76+ VGPRs
// at 512 threads, while 1024-thread blocks get hard-capped at 64 VGPRs
// (r3/r4/r5: 21 GB of scratch spill traffic regardless of launch_bounds or
// amdgpu_waves_per_eu hints). DO NOT move to 1024-thread blocks.
extern "C" __global__ void __launch_bounds__(512, 2)
nca_fused(const float* __restrict__ x, const float* __restrict__ pw1,
          const float* __restrict__ pb1, const float* __restrict__ pw2,
          const float* __restrict__ pb2, const float* __restrict__ cw,
          const float* __restrict__ cb, float* __restrict__ out) {
  extern __shared__ float4 ldsv[];
  float* lds = (float*)ldsv;  // runtime cast: keeps initializers non-constant
  const int tid = threadIdx.x;
  const int bid = blockIdx.x;

  float* S0[2] = {lds, lds + 16384};
  float* S1[2] = {lds + 32768, lds + 34816};
  float* S2[2] = {lds + 36864, lds + 37120};

  // ---- init buffer 0 only (buffer "next" is fully rewritten every step)
  {
    float4* z0 = (float4*)S0[0];
#pragma unroll
    for (int i = 0; i < 8; ++i) z0[tid + 512 * i] = zero4();  // 4096 float4
    ((float4*)S1[0])[tid] = zero4();                          // 512 float4
    if (tid < 64) ((float4*)S2[0])[tid] = zero4();            // 64 float4
  }
  __syncthreads();
  if (tid < 256) {  // set_input: (x>0.5) into ch0 of d=8 slab
    float v = x[bid * 256 + tid];
    int i = tid >> 4, j = tid & 15;
    S0[0][ix0(i, j, 8)] = (v > 0.5f) ? 1.0f : 0.0f;
  }
  __syncthreads();

  // 2x2x2-group (level 0) == level-1 cell index space
  const int ga = tid >> 6, gb = (tid >> 3) & 7, gd = tid & 7;

#pragma unroll 1
  for (int t = 0; t < 15; ++t) {
    const int cur = t & 1;
    const float* s0c = S0[cur];
    float* s0n = S0[cur ^ 1];
    const float* s1c = S1[cur];
    float* s1n = S1[cur ^ 1];
    const float* s2c = S2[cur];
    float* s2n = S2[cur ^ 1];

    // ---------------- level 0: 2x2x2 group per thread, 16-wide halves ----------------
    {
      const float* W1 = pw1;  // (16,32)
      const float* W2 = pw2;  // (32,4)
      // fold bias + above-contribution once per group, per 16-wide half
      float4 ab = ld4(s1c + ix1(ga, gb, gd));
      float ac0[16], ac1[16];
#pragma unroll
      for (int j = 0; j < 16; ++j) ac0[j] = fmaf(ab.x, W1[384 + j], pb1[j]);
      fma_row16(ac0, ab.y, W1 + 416);
      fma_row16(ac0, ab.z, W1 + 448);
      fma_row16(ac0, ab.w, W1 + 480);
#pragma unroll
      for (int j = 0; j < 16; ++j) ac1[j] = fmaf(ab.x, W1[384 + 16 + j], pb1[16 + j]);
      fma_row16(ac1, ab.y, W1 + 416 + 16);
      fma_row16(ac1, ab.z, W1 + 448 + 16);
      fma_row16(ac1, ab.w, W1 + 480 + 16);

#pragma unroll 1
      for (int cell = 0; cell < 8; ++cell) {
        int a = 2 * ga + (cell >> 2);
        int b = 2 * gb + ((cell >> 1) & 1);
        int d = 2 * gd + (cell & 1);
        float4 c4 = ld4(s0c + ix0(a, b, d));
        float4 nb = zero4();
        if (a > 0) nb = add4(nb, ld4(s0c + ix0(a - 1, b, d)));
        if (a < 15) nb = add4(nb, ld4(s0c + ix0(a + 1, b, d)));
        if (b > 0) nb = add4(nb, ld4(s0c + ix0(a, b - 1, d)));
        if (b < 15) nb = add4(nb, ld4(s0c + ix0(a, b + 1, d)));
        if (d > 0) nb = add4(nb, ld4(s0c + ix0(a, b, d - 1)));
        if (d < 15) nb = add4(nb, ld4(s0c + ix0(a, b, d + 1)));
        float d0 = pb2[0], d1 = pb2[1], d2 = pb2[2], d3 = pb2[3];
        {  // half 0
          float hid[16];
#pragma unroll
          for (int j = 0; j < 16; ++j) hid[j] = ac0[j];
          p_rows16(hid, c4, nb, W1);  // below==0 at level 0
          tail16(hid, W2, d0, d1, d2, d3);
        }
        {  // half 1
          float hid[16];
#pragma unroll
          for (int j = 0; j < 16; ++j) hid[j] = ac1[j];
          p_rows16(hid, c4, nb, W1 + 16);
          tail16(hid, W2 + 64, d0, d1, d2, d3);
        }
        st4(s0n + ix0(a, b, d), clip_res(c4, d0, d1, d2, d3));
      }
    }

    // ---------------- level 1: one cell per thread, 16-wide halves ----------------
    {
      const float* W1 = pw1 + 512;
      const float* W2 = pw2 + 128;
      const float* B1 = pb1 + 32;
      const float* B2 = pb2 + 4;
      float4 c4 = ld4(s1c + ix1(ga, gb, gd));
      float4 nb = zero4();
      if (ga > 0) nb = add4(nb, ld4(s1c + ix1(ga - 1, gb, gd)));
      if (ga < 7) nb = add4(nb, ld4(s1c + ix1(ga + 1, gb, gd)));
      if (gb > 0) nb = add4(nb, ld4(s1c + ix1(ga, gb - 1, gd)));
      if (gb < 7) nb = add4(nb, ld4(s1c + ix1(ga, gb + 1, gd)));
      if (gd > 0) nb = add4(nb, ld4(s1c + ix1(ga, gb, gd - 1)));
      if (gd < 7) nb = add4(nb, ld4(s1c + ix1(ga, gb, gd + 1)));
      float4 bl = zero4();
#pragma unroll
      for (int q = 0; q < 8; ++q)
        bl = add4(bl, ld4(s0c + ix0(2 * ga + (q >> 2), 2 * gb + ((q >> 1) & 1),
                                    2 * gd + (q & 1))));
      bl.x *= 0.125f; bl.y *= 0.125f; bl.z *= 0.125f; bl.w *= 0.125f;
      float4 ab = ld4(s2c + ix2(ga >> 1, gb >> 1, gd >> 1));
      float d0 = B2[0], d1 = B2[1], d2 = B2[2], d3 = B2[3];
#pragma unroll
      for (int h = 0; h < 2; ++h) {
        const float* W1h = W1 + 16 * h;
        float hid[16];
#pragma unroll
        for (int j = 0; j < 16; ++j) hid[j] = B1[16 * h + j];
        p_rows16(hid, c4, nb, W1h);
        fma_row16(hid, bl.x, W1h + 8 * 32);
        fma_row16(hid, bl.y, W1h + 9 * 32);
        fma_row16(hid, bl.z, W1h + 10 * 32);
        fma_row16(hid, bl.w, W1h + 11 * 32);
        fma_row16(hid, ab.x, W1h + 12 * 32);
        fma_row16(hid, ab.y, W1h + 13 * 32);
        fma_row16(hid, ab.z, W1h + 14 * 32);
        fma_row16(hid, ab.w, W1h + 15 * 32);
        tail16(hid, W2 + 64 * h, d0, d1, d2, d3);
      }
      st4(s1n + ix1(ga, gb, gd), clip_res(c4, d0, d1, d2, d3));
    }

    // ---------------- level 2: one cell per thread (tid<64), 16-wide halves ----------------
    if (tid < 64) {
      const float* W1 = pw1 + 1024;
      const float* W2 = pw2 + 256;
      const float* B1 = pb1 + 64;
      const float* B2 = pb2 + 8;
      int a = tid >> 4, b = (tid >> 2) & 3, d = tid & 3;
      float4 c4 = ld4(s2c + ix2(a, b, d));
      float4 nb = zero4();
      if (a > 0) nb = add4(nb, ld4(s2c + ix2(a - 1, b, d)));
      if (a < 3) nb = add4(nb, ld4(s2c + ix2(a + 1, b, d)));
      if (b > 0) nb = add4(nb, ld4(s2c + ix2(a, b - 1, d)));
      if (b < 3) nb = add4(nb, ld4(s2c + ix2(a, b + 1, d)));
      if (d > 0) nb = add4(nb, ld4(s2c + ix2(a, b, d - 1)));
      if (d < 3) nb = add4(nb, ld4(s2c + ix2(a, b, d + 1)));
      float4 bl = zero4();
#pragma unroll
      for (int q = 0; q < 8; ++q)
        bl = add4(bl, ld4(s1c + ix1(2 * a + (q >> 2), 2 * b + ((q >> 1) & 1),
                                    2 * d + (q & 1))));
      bl.x *= 0.125f; bl.y *= 0.125f; bl.z *= 0.125f; bl.w *= 0.125f;
      float d0 = B2[0], d1 = B2[1], d2 = B2[2], d3 = B2[3];
#pragma unroll
      for (int h = 0; h < 2; ++h) {
        const float* W1h = W1 + 16 * h;
        float hid[16];
#pragma unroll
        for (int j = 0; j < 16; ++j) hid[j] = B1[16 * h + j];
        p_rows16(hid, c4, nb, W1h);
        fma_row16(hid, bl.x, W1h + 8 * 32);
        fma_row16(hid, bl.y, W1h + 9 * 32);
        fma_row16(hid, bl.z, W1h + 10 * 32);
        fma_row16(hid, bl.w, W1h + 11 * 32);
        // above == 0 at top level
        tail16(hid, W2 + 64 * h, d0, d1, d2, d3);
      }
      st4(s2n + ix2(a, b, d), clip_res(c4, d0, d1, d2, d3));
    }

    __syncthreads();  // reads from [cur], writes to [cur^1]: one barrier per step
  }

  // ---------------- classifier: feats(256) @ cls_w(256,10) + cls_b ----------------
  if (tid < 256) {
    double v = (double)S2[1][tid];  // 15 steps -> buffer 1; linear == reshape order
    const float* wr = cw + tid * 10;
    double p[10];
#pragma unroll
    for (int o = 0; o < 10; ++o) p[o] = v * (double)wr[o];
#pragma unroll
    for (int off = 32; off > 0; off >>= 1) {
#pragma unroll
      for (int o = 0; o < 10; ++o) p[o] += __shfl_down(p[o], off);
    }
    if ((tid & 63) == 0) {
      double* red = (double*)S0[0];  // dead after the loop; 40 doubles
      int wv = tid >> 6;
#pragma unroll
      for (int o = 0; o < 10; ++o) red[wv * 10 + o] = p[o];
    }
  }
  __syncthreads();
  if (tid < 10) {
    const double* red = (const double*)S0[0];
    double r = (double)cb[tid] + red[tid] + red[10 + tid] + red[20 + tid] + red[30 + tid];
    out[bid * 10 + tid] = (float)r;
  }
}

extern "C" void kernel_launch(void* const* d_in, const int* in_sizes, int n_in,
                              void* d_out, int out_size, void* d_ws, size_t ws_size,
                              hipStream_t stream) {
  const float* x = (const float*)d_in[0];
  const float* w1 = (const float*)d_in[1];
  const float* b1 = (const float*)d_in[2];
  const float* w2 = (const float*)d_in[3];
  const float* b2 = (const float*)d_in[4];
  const float* cw = (const float*)d_in[5];
  const float* cb = (const float*)d_in[6];
  float* out = (float*)d_out;

  const int B = in_sizes[0] / 256;             // 2048
  const size_t shmem = 37376 * sizeof(float);  // 149504 B
  (void)hipFuncSetAttribute((const void*)nca_fused,
                            hipFuncAttributeMaxDynamicSharedMemorySize, (int)shmem);
  nca_fused<<<dim3(B), dim3(512), shmem, stream>>>(x, w1, b1, w2, b2, cw, cb, out);
}